// Round 4
// baseline (1508.897 us; speedup 1.0000x reference)
//
#include <hip/hip_runtime.h>

#define H  1024
#define V  512
#define WV 300
#define S  64
#define N  512

#define KP 8     // split-K parts
#define KC 64    // K chunk staged in LDS

// ---- workspace float offsets ----
#define WS_HALL   0                         // [S,H]
#define WS_CAT    (S*H)                     // [S,1536]  (hat | ac)
#define WS_W2V    (WS_CAT + S*1536)         // [S,H]
#define WS_CHOICE (WS_W2V + S*H)            // [S,2]
#define WS_SCAL   (WS_CHOICE + 2*S)         // [S]
#define WS_ACSUM  (WS_SCAL + S)             // [S]
#define WS_KT     (WS_ACSUM + S)            // [S,H]
#define WS_ATT    (WS_KT + S*H)             // [S,N]
#define WS_SLOTP  (WS_ATT + S*N)            // [2][8][1024] partial bar_et slots
#define WS_SLOTA  (WS_SLOTP + 2*8*1024)     // [2][8] partial asum slots
#define WS_CTR    (WS_SLOTA + 16)           // [1]

// ---- out float offsets ----
#define OUT_EP   0                  // [S,N]
#define OUT_AC   (S*N)              // [S,V]
#define OUT_SE   (S*N + S*V)        // [S,H]
#define OUT_ALL  (OUT_SE + S*H)     // [S,N,H]
#define OUT_ACT  (OUT_ALL + (size_t)S*N*H) // [S,WV]

__device__ __forceinline__ float dot4(float4 a, float4 b) {
  return a.x*b.x + a.y*b.y + a.z*b.z + a.w*b.w;
}

// ---------------------------------------------------------------------------
// Split-K tiled NT GEMM partial: P[mat][kp][64][Ntot-slice] = X[:,kslice] @ W^T
// grid = (jtiles, KP, nmats). Bias/activation deferred to epilogue.
// ---------------------------------------------------------------------------
struct SKArgs {
  const float* X; const float* W0; const float* W1;
  float* pbuf;
  int ldx, K, KS, Ntot;
};

__global__ __launch_bounds__(256) void g_split(SKArgs a) {
  __shared__ float Xs[64][KC + 4];
  __shared__ float Ws[64][KC + 4];
  const int tid = threadIdx.x;
  const int jt = blockIdx.x, kp = blockIdx.y, mat = blockIdx.z;
  const float* W = mat ? a.W1 : a.W0;
  const int jbase = jt * 64, kbase = kp * a.KS;
  const int tm = tid >> 5, tn = tid & 31;
  float acc[8][2];
#pragma unroll
  for (int i = 0; i < 8; ++i) acc[i][0] = acc[i][1] = 0.f;
  const int lr = tid >> 2;
  const int lc = (tid & 3) * 16;
  const float* xrow = a.X + (size_t)lr * a.ldx + kbase + lc;
  const float* wrow = W + (size_t)(jbase + lr) * a.K + kbase + lc;
  float4 xv0, xv1, xv2, xv3, wv0, wv1, wv2, wv3;
  xv0 = ((const float4*)xrow)[0]; xv1 = ((const float4*)xrow)[1];
  xv2 = ((const float4*)xrow)[2]; xv3 = ((const float4*)xrow)[3];
  wv0 = ((const float4*)wrow)[0]; wv1 = ((const float4*)wrow)[1];
  wv2 = ((const float4*)wrow)[2]; wv3 = ((const float4*)wrow)[3];
  for (int k0 = 0; k0 < a.KS; k0 += KC) {
    __syncthreads();
    *(float4*)&Xs[lr][lc +  0] = xv0; *(float4*)&Xs[lr][lc +  4] = xv1;
    *(float4*)&Xs[lr][lc +  8] = xv2; *(float4*)&Xs[lr][lc + 12] = xv3;
    *(float4*)&Ws[lr][lc +  0] = wv0; *(float4*)&Ws[lr][lc +  4] = wv1;
    *(float4*)&Ws[lr][lc +  8] = wv2; *(float4*)&Ws[lr][lc + 12] = wv3;
    __syncthreads();
    if (k0 + KC < a.KS) {
      const float* xp = xrow + k0 + KC;
      const float* wp = wrow + k0 + KC;
      xv0 = ((const float4*)xp)[0]; xv1 = ((const float4*)xp)[1];
      xv2 = ((const float4*)xp)[2]; xv3 = ((const float4*)xp)[3];
      wv0 = ((const float4*)wp)[0]; wv1 = ((const float4*)wp)[1];
      wv2 = ((const float4*)wp)[2]; wv3 = ((const float4*)wp)[3];
    }
#pragma unroll
    for (int kk = 0; kk < KC; kk += 4) {
      float4 w0 = *(const float4*)&Ws[tn][kk];
      float4 w1 = *(const float4*)&Ws[tn + 32][kk];
#pragma unroll
      for (int i = 0; i < 8; ++i) {
        float4 x = *(const float4*)&Xs[tm * 8 + i][kk];
        acc[i][0] += dot4(x, w0);
        acc[i][1] += dot4(x, w1);
      }
    }
  }
  float* base = a.pbuf + ((size_t)(mat * KP + kp) * 64) * a.Ntot + jbase;
#pragma unroll
  for (int i = 0; i < 8; ++i) {
    const int r = tm * 8 + i;
    base[(size_t)r * a.Ntot + tn]      = acc[i][0];
    base[(size_t)r * a.Ntot + tn + 32] = acc[i][1];
  }
}

// Epilogue: sum KP partials + bias + activation, scatter to 1-2 outputs.
struct EPArgs {
  const float* pbuf;
  const float* B0; const float* B1;
  float* o1_0; float* o2_0; float* o1_1; float* o2_1;
  int nsh, ld1_0, ld2_0, ld1_1, ld2_1, act;
};

__global__ __launch_bounds__(256) void ep_k(EPArgs e) {
  const int mat = blockIdx.y;
  const int Ntot = 1 << e.nsh;
  const int idx = blockIdx.x * 256 + threadIdx.x;
  const int r = idx >> e.nsh, j = idx & (Ntot - 1);
  const float* pb = e.pbuf + (size_t)mat * KP * 64 * Ntot;
  float s = 0.f;
#pragma unroll
  for (int kp = 0; kp < KP; ++kp) s += pb[(size_t)(kp * 64 + r) * Ntot + j];
  s += (mat ? e.B1 : e.B0)[j];
  if (e.act == 1) s = fmaxf(s, 0.f);
  else if (e.act == 2) s = 1.f / (1.f + __expf(-s));
  float* o1 = mat ? e.o1_1 : e.o1_0;
  float* o2 = mat ? e.o2_1 : e.o2_0;
  const int ld1 = mat ? e.ld1_1 : e.ld1_0;
  const int ld2 = mat ? e.ld2_1 : e.ld2_0;
  o1[(size_t)r * ld1 + j] = s;
  if (o2) o2[(size_t)r * ld2 + j] = s;
}

// choice softmax (c0,c1) and acsum. hat read from cat (stride 1536).
__global__ void k_choice(const float* __restrict__ cat, const float* __restrict__ out_ac,
                         const float* __restrict__ W3w, const float* __restrict__ W3b,
                         float* __restrict__ ws) {
  int t = blockIdx.x, tid = threadIdx.x;
  const float* hat = cat + (size_t)t * 1536;
  float4 h4 = *(const float4*)(hat + tid * 4);
  float p[4];
#pragma unroll
  for (int r = 0; r < 3; ++r) {
    float4 w4 = *(const float4*)(W3w + (size_t)r * H + tid * 4);
    p[r] = dot4(h4, w4);
  }
  const float* ac = out_ac + (size_t)t * V;
  p[3] = ac[tid * 2] + ac[tid * 2 + 1];
  __shared__ float red[4][256];
#pragma unroll
  for (int q = 0; q < 4; ++q) red[q][tid] = p[q];
  __syncthreads();
  for (int sft = 128; sft > 0; sft >>= 1) {
    if (tid < sft) {
#pragma unroll
      for (int q = 0; q < 4; ++q) red[q][tid] += red[q][tid + sft];
    }
    __syncthreads();
  }
  if (tid == 0) {
    float l0 = red[0][0] + W3b[0], l1 = red[1][0] + W3b[1], l2 = red[2][0] + W3b[2];
    float m  = fmaxf(l0, fmaxf(l1, l2));
    float e0 = __expf(l0 - m), e1 = __expf(l1 - m), e2 = __expf(l2 - m);
    float inv = 1.f / (e0 + e1 + e2);
    ws[WS_CHOICE + t * 2]     = e0 * inv;
    ws[WS_CHOICE + t * 2 + 1] = e1 * inv;
    ws[WS_ACSUM + t]          = red[3][0];
  }
}

// bar_ft = (ac/acsum)@emb -> out_act, plus scal = bar_ft@W4w + W4b (folded).
__global__ __launch_bounds__(256) void k_barft(
    const float* __restrict__ out_ac, const float* __restrict__ emb,
    const float* __restrict__ ws_ro, const float* __restrict__ W4w,
    const float* __restrict__ W4b, float* __restrict__ out_act,
    float* __restrict__ ws) {
  int t = blockIdx.x, tid = threadIdx.x;
  __shared__ float acS[V];
  const float* ac = out_ac + (size_t)t * V;
  acS[tid] = ac[tid];
  acS[tid + 256] = ac[tid + 256];
  __syncthreads();
  float s0 = 0.f, s1 = 0.f;
  const int w0 = tid, w1 = 256 + tid;
  for (int v = 0; v < V; ++v) {
    float a = acS[v];
    const float* er = emb + (size_t)v * WV;
    s0 += a * er[w0];
    if (tid < WV - 256) s1 += a * er[w1];
  }
  float inv = 1.f / ws_ro[WS_ACSUM + t];
  s0 *= inv; s1 *= inv;
  out_act[(size_t)t * WV + w0] = s0;
  if (tid < WV - 256) out_act[(size_t)t * WV + w1] = s1;
  float p = s0 * W4w[w0] + (tid < WV - 256 ? s1 * W4w[w1] : 0.f);
  __shared__ float red[256];
  red[tid] = p;
  __syncthreads();
  for (int s = 128; s > 0; s >>= 1) {
    if (tid < s) red[tid] += red[tid + s];
    __syncthreads();
  }
  if (tid == 0) ws[WS_SCAL + t] = red[0] + W4b[0];
}

// ---------------------------------------------------------------------------
// Sequential scan: 8 blocks x 1024 threads. Block g owns rows g*64..+63.
// Thread (rg=tid>>8, c=tid&255) owns ev[rows rg*16..+15][cols 4c..4c+3] in
// registers (16 float4). No atomics: per-block partials -> private slots
// (double-buffered by step parity), phase-2 sums 8 slots.
// ---------------------------------------------------------------------------
__global__ __launch_bounds__(1024, 1) void k_seq(
    const float* __restrict__ ev0, const float* __restrict__ ws,
    float* __restrict__ slotP, float* __restrict__ slotA, unsigned* __restrict__ ctr,
    float* __restrict__ att, float* __restrict__ ktb,
    float* __restrict__ out_ep, float* __restrict__ out_se) {
  const int g = blockIdx.x, tid = threadIdx.x;
  const int c = tid & 255, rg = tid >> 8;
  const int col = c * 4;
  const int wave = tid >> 6, lane = tid & 63;
  __shared__ float dpred[16][16];
  __shared__ float attnS[64], prevS[64];
  __shared__ alignas(16) float parts[3][256][4];
  if (tid < 64) prevS[tid] = 0.f;
  float4 ev[16];
#pragma unroll
  for (int i = 0; i < 16; ++i)
    ev[i] = *(const float4*)(ev0 + (size_t)(g * 64 + rg * 16 + i) * H + col);
  __syncthreads();
  unsigned target = 0;
  for (int t = 0; t < S; ++t) {
    const int buf = t & 1;
    // ---- dots: dp[i] = partial of ev[row]·w2v over this thread's 4 cols ----
    const float4 w4 = *(const float4*)(ws + WS_W2V + (size_t)t * H + col);
    float dp[16];
#pragma unroll
    for (int i = 0; i < 16; ++i) dp[i] = dot4(ev[i], w4);
#pragma unroll
    for (int m = 32; m > 0; m >>= 1) {
#pragma unroll
      for (int i = 0; i < 16; ++i) dp[i] += __shfl_xor(dp[i], m, 64);
    }
    if (lane == 0) {
#pragma unroll
      for (int i = 0; i < 16; ++i) dpred[wave][i] = dp[i];
    }
    __syncthreads();                      // (a)
    if (tid < 64) {
      const int r = tid, rgr = r >> 4, ri = r & 15;
      float d = dpred[rgr * 4][ri] + dpred[rgr * 4 + 1][ri]
              + dpred[rgr * 4 + 2][ri] + dpred[rgr * 4 + 3][ri];
      float ep = 1.f / (1.f + __expf(-d));
      out_ep[(size_t)t * N + g * 64 + r] = ep;
      float a = ws[WS_CHOICE + 2 * t] * ep + ws[WS_CHOICE + 2 * t + 1] * prevS[r];
      prevS[r] = ep;
      attnS[r] = a;
      att[(size_t)t * N + g * 64 + r] = a;
      float s = a;
#pragma unroll
      for (int m = 32; m > 0; m >>= 1) s += __shfl_xor(s, m, 64);
      if (tid == 0)
        __hip_atomic_store(slotA + buf * 8 + g, s, __ATOMIC_RELAXED, __HIP_MEMORY_SCOPE_AGENT);
    }
    __syncthreads();                      // (b)
    float atl[16];
#pragma unroll
    for (int i = 0; i < 16; ++i) atl[i] = attnS[rg * 16 + i];
    float4 pv = make_float4(0.f, 0.f, 0.f, 0.f);
#pragma unroll
    for (int i = 0; i < 16; ++i) {
      pv.x += atl[i] * ev[i].x; pv.y += atl[i] * ev[i].y;
      pv.z += atl[i] * ev[i].z; pv.w += atl[i] * ev[i].w;
    }
    if (rg > 0) *(float4*)&parts[rg - 1][c][0] = pv;
    __syncthreads();                      // (c)
    if (rg == 0) {
#pragma unroll
      for (int j = 0; j < 3; ++j) {
        float4 q = *(const float4*)&parts[j][c][0];
        pv.x += q.x; pv.y += q.y; pv.z += q.z; pv.w += q.w;
      }
      float* sp = slotP + (size_t)(buf * 8 + g) * 1024 + col;
      __hip_atomic_store(sp + 0, pv.x, __ATOMIC_RELAXED, __HIP_MEMORY_SCOPE_AGENT);
      __hip_atomic_store(sp + 1, pv.y, __ATOMIC_RELAXED, __HIP_MEMORY_SCOPE_AGENT);
      __hip_atomic_store(sp + 2, pv.z, __ATOMIC_RELAXED, __HIP_MEMORY_SCOPE_AGENT);
      __hip_atomic_store(sp + 3, pv.w, __ATOMIC_RELAXED, __HIP_MEMORY_SCOPE_AGENT);
    }
    // ---- grid barrier (8 participants) ----
    __syncthreads();
    target += (unsigned)gridDim.x;
    if (tid == 0) {
      __hip_atomic_fetch_add(ctr, 1u, __ATOMIC_RELEASE, __HIP_MEMORY_SCOPE_AGENT);
      while (__hip_atomic_load(ctr, __ATOMIC_RELAXED, __HIP_MEMORY_SCOPE_AGENT) < target) {}
      (void)__hip_atomic_load(ctr, __ATOMIC_ACQUIRE, __HIP_MEMORY_SCOPE_AGENT);
    }
    __syncthreads();                      // (d)
    // ---- phase 2: sum 8 slots -> bar_et, kt; update ev ----
    float4 bar = make_float4(0.f, 0.f, 0.f, 0.f);
    float asv = 0.f;
#pragma unroll
    for (int b = 0; b < 8; ++b) {
      const float* sp = slotP + (size_t)(buf * 8 + b) * 1024 + col;
      bar.x += __hip_atomic_load(sp + 0, __ATOMIC_RELAXED, __HIP_MEMORY_SCOPE_AGENT);
      bar.y += __hip_atomic_load(sp + 1, __ATOMIC_RELAXED, __HIP_MEMORY_SCOPE_AGENT);
      bar.z += __hip_atomic_load(sp + 2, __ATOMIC_RELAXED, __HIP_MEMORY_SCOPE_AGENT);
      bar.w += __hip_atomic_load(sp + 3, __ATOMIC_RELAXED, __HIP_MEMORY_SCOPE_AGENT);
      asv   += __hip_atomic_load(slotA + buf * 8 + b, __ATOMIC_RELAXED, __HIP_MEMORY_SCOPE_AGENT);
    }
    float inv = 1.f / asv;
    bar.x *= inv; bar.y *= inv; bar.z *= inv; bar.w *= inv;
    float sc = ws[WS_SCAL + t];
    float4 kt = make_float4(fmaxf(sc * bar.x, 0.f), fmaxf(sc * bar.y, 0.f),
                            fmaxf(sc * bar.z, 0.f), fmaxf(sc * bar.w, 0.f));
    if (g == 0 && rg == 0) {
      *(float4*)(out_se + (size_t)t * H + col) = bar;
      *(float4*)(ktb + (size_t)t * H + col) = kt;
    }
#pragma unroll
    for (int i = 0; i < 16; ++i) {
      float a = atl[i];
      ev[i].x = a * kt.x + (1.f - a) * ev[i].x;
      ev[i].y = a * kt.y + (1.f - a) * ev[i].y;
      ev[i].z = a * kt.z + (1.f - a) * ev[i].z;
      ev[i].w = a * kt.w + (1.f - a) * ev[i].w;
    }
  }
}

// Reconstruct out_all[t,n,:] from ev0, attn, kt: per-row affine scan.
__global__ __launch_bounds__(256) void k_recon(
    const float* __restrict__ ev0, const float* __restrict__ att,
    const float* __restrict__ ktb, float* __restrict__ out_all) {
  const int n = blockIdx.x, tid = threadIdx.x;
  const int col = tid * 4;
  __shared__ float aS[S];
  if (tid < S) aS[tid] = att[(size_t)tid * N + n];
  float4 v = *(const float4*)(ev0 + (size_t)n * H + col);
  __syncthreads();
  for (int t = 0; t < S; ++t) {
    float a = aS[t];
    float4 k4 = *(const float4*)(ktb + (size_t)t * H + col);
    v.x = a * k4.x + (1.f - a) * v.x;
    v.y = a * k4.y + (1.f - a) * v.y;
    v.z = a * k4.z + (1.f - a) * v.z;
    v.w = a * k4.w + (1.f - a) * v.w;
    *(float4*)(out_all + ((size_t)t * N + n) * H + col) = v;
  }
}

extern "C" void kernel_launch(void* const* d_in, const int* in_sizes, int n_in,
                              void* d_out, int out_size, void* d_ws, size_t ws_size,
                              hipStream_t stream) {
  const float* vv  = (const float*)d_in[0];
  const float* ev0 = (const float*)d_in[1];
  const float* A1w = (const float*)d_in[2];
  const float* A1b = (const float*)d_in[3];
  const float* A2w = (const float*)d_in[4];
  const float* A2b = (const float*)d_in[5];
  const float* emb = (const float*)d_in[6];
  const float* W1w = (const float*)d_in[7];
  const float* W1b = (const float*)d_in[8];
  const float* W2w = (const float*)d_in[9];
  const float* W2b = (const float*)d_in[10];
  const float* W3w = (const float*)d_in[11];
  const float* W3b = (const float*)d_in[12];
  const float* W4w = (const float*)d_in[13];
  const float* W4b = (const float*)d_in[14];

  float* ws  = (float*)d_ws;
  float* out = (float*)d_out;
  float* out_ep  = out + OUT_EP;
  float* out_ac  = out + OUT_AC;
  float* out_se  = out + OUT_SE;
  float* out_all = out + OUT_ALL;
  float* out_act = out + OUT_ACT;
  float* cat = ws + WS_CAT;
  float* P   = out_all;   // gemm partial scratch: out_all written only by k_recon at the end

  hipMemsetAsync(ws + WS_CTR, 0, sizeof(unsigned), stream);

  // Stage 1: Hall = relu(vv@A1w^T+A1b); hat = relu(vv@W1w^T+W1b) -> cat
  {
    SKArgs a{vv, A1w, W1w, P, H, H, H / KP, H};
    g_split<<<dim3(16, KP, 2), 256, 0, stream>>>(a);
    EPArgs e{P, A1b, W1b, ws + WS_HALL, nullptr, cat, nullptr, 10, H, 0, 1536, 0, 1};
    ep_k<<<dim3(256, 2), 256, 0, stream>>>(e);
  }
  // Stage 2: ac = sigmoid(Hall@A2w^T+A2b) -> out_ac and cat[:,1024:]
  {
    SKArgs a{ws + WS_HALL, A2w, A2w, P, H, H, H / KP, V};
    g_split<<<dim3(8, KP, 1), 256, 0, stream>>>(a);
    EPArgs e{P, A2b, A2b, out_ac, cat + H, nullptr, nullptr, 9, V, 1536, 0, 0, 2};
    ep_k<<<dim3(128, 1), 256, 0, stream>>>(e);
  }
  k_choice<<<S, 256, 0, stream>>>(cat, out_ac, W3w, W3b, ws);
  // Stage 3: w2v = cat@W2w^T + W2b
  {
    SKArgs a{cat, W2w, W2w, P, 1536, 1536, 1536 / KP, H};
    g_split<<<dim3(16, KP, 1), 256, 0, stream>>>(a);
    EPArgs e{P, W2b, W2b, ws + WS_W2V, nullptr, nullptr, nullptr, 10, H, 0, 0, 0, 0};
    ep_k<<<dim3(256, 1), 256, 0, stream>>>(e);
  }
  k_barft<<<S, 256, 0, stream>>>(out_ac, emb, ws, W4w, W4b, out_act, ws);
  k_seq<<<8, 1024, 0, stream>>>(ev0, ws, ws + WS_SLOTP, ws + WS_SLOTA,
                                (unsigned*)(ws + WS_CTR),
                                ws + WS_ATT, ws + WS_KT, out_ep, out_se);
  k_recon<<<N, 256, 0, stream>>>(ev0, ws + WS_ATT, ws + WS_KT, out_all);
}